// Round 7
// baseline (194.943 us; speedup 1.0000x reference)
//
#include <hip/hip_runtime.h>

#define EPSF 1e-12f
#define GN 32
#define NPTS (GN * GN * GN)
#define NCOL (GN * GN)
#define FSPLIT 16   // face-splits
#define NCG 16      // column-groups of 64 columns
#define NBLK (NCG * FSPLIT)
#define NTHR 1024
#define FS 20       // floats per face record

__device__ __forceinline__ float dot_rn(const float* x, const float* y) {
    return __fadd_rn(__fadd_rn(__fmul_rn(x[0], y[0]), __fmul_rn(x[1], y[1])),
                     __fmul_rn(x[2], y[2]));
}
__device__ __forceinline__ float wmin64(float v) {
    for (int o = 32; o > 0; o >>= 1) v = fminf(v, __shfl_xor(v, o));
    return v;
}
__device__ __forceinline__ float wmax64(float v) {
    for (int o = 32; o > 0; o >>= 1) v = fmaxf(v, __shfl_xor(v, o));
    return v;
}
__device__ __forceinline__ float wsum64(float v) {
    for (int o = 32; o > 0; o >>= 1) v += __shfl_xor(v, o);
    return v;
}

// ws layout (memset 0xFF covers d2u/parm/counter): [d2u][parm][counter+pad][fd]
// Face records go to GLOBAL fd and are read back with wave-uniform addresses ->
// s_load -> SGPRs. R4 evidence: same math with face fields in SGPRs ran at
// VALUBusy 67% vs 34% when they occupy VGPRs (dmin[32] leaves no room for ILP).
__global__ void __launch_bounds__(NTHR) k_all(
    const float* __restrict__ hv, int nh,
    const float* __restrict__ ov, int no,
    const int* __restrict__ faces, int nf,
    unsigned* __restrict__ d2u, unsigned* __restrict__ parm,
    unsigned* __restrict__ counter, float* __restrict__ fd,
    float* __restrict__ out)
{
    __shared__ unsigned s_d2[2048];
    __shared__ unsigned s_pm[64];
    __shared__ float s_w[16][8];
    __shared__ float s_hdr[4];
    __shared__ float s_hb[6];
    __shared__ unsigned s_last;
    __shared__ float s_ovl;

    int t = threadIdx.x, lane = t & 63, wvid = t >> 6;
    int fs = blockIdx.x >> 4;   // face-split id
    int cg = blockIdx.x & 15;   // column-group id
    const float step = 2.0f / 31.0f;

    // ---------- phase A: human bbox -> center/scale (redundant per block) ----------
    {
        float mnx = INFINITY, mny = INFINITY, mnz = INFINITY;
        float mxx = -INFINITY, mxy = -INFINITY, mxz = -INFINITY;
        for (int i = t; i < nh; i += NTHR) {
            float x = hv[3 * i], y = hv[3 * i + 1], z = hv[3 * i + 2];
            mnx = fminf(mnx, x); mny = fminf(mny, y); mnz = fminf(mnz, z);
            mxx = fmaxf(mxx, x); mxy = fmaxf(mxy, y); mxz = fmaxf(mxz, z);
        }
        mnx = wmin64(mnx); mny = wmin64(mny); mnz = wmin64(mnz);
        mxx = wmax64(mxx); mxy = wmax64(mxy); mxz = wmax64(mxz);
        if (lane == 0) {
            s_w[wvid][0] = mnx; s_w[wvid][1] = mny; s_w[wvid][2] = mnz;
            s_w[wvid][3] = mxx; s_w[wvid][4] = mxy; s_w[wvid][5] = mxz;
        }
        __syncthreads();
        if (wvid == 0) {
            float a0 = (lane < 16) ? s_w[lane][0] : INFINITY;
            float a1 = (lane < 16) ? s_w[lane][1] : INFINITY;
            float a2 = (lane < 16) ? s_w[lane][2] : INFINITY;
            float a3 = (lane < 16) ? s_w[lane][3] : -INFINITY;
            float a4 = (lane < 16) ? s_w[lane][4] : -INFINITY;
            float a5 = (lane < 16) ? s_w[lane][5] : -INFINITY;
            a0 = wmin64(a0); a1 = wmin64(a1); a2 = wmin64(a2);
            a3 = wmax64(a3); a4 = wmax64(a4); a5 = wmax64(a5);
            if (lane == 0) {
                float e0 = __fsub_rn(a3, a0);
                float e1 = __fsub_rn(a4, a1);
                float e2 = __fsub_rn(a5, a2);
                float m = fmaxf(e0, fmaxf(e1, e2));
                s_hdr[0] = __fmul_rn(0.5f, __fadd_rn(a0, a3));
                s_hdr[1] = __fmul_rn(0.5f, __fadd_rn(a1, a4));
                s_hdr[2] = __fmul_rn(0.5f, __fadd_rn(a2, a5));
                s_hdr[3] = __fmul_rn(0.6f, m);
                s_hb[0] = a0; s_hb[1] = a1; s_hb[2] = a2;
                s_hb[3] = a3; s_hb[4] = a4; s_hb[5] = a5;
            }
        }
        __syncthreads();
    }
    float cx = s_hdr[0], cy = s_hdr[1], cz = s_hdr[2], sc = s_hdr[3];

    // ---------- phase B: this split's face records -> GLOBAL fd ----------
    // The 16 cg-blocks sharing this fs write bit-identical duplicates (same
    // inputs, same ops) -> benign racing writes. Each block reads back only
    // what it wrote itself, through its own XCD L2 (visible after
    // __syncthreads' vmcnt(0) drain).
    int chunkB = (nf + FSPLIT - 1) / FSPLIT;
    int f0B = fs * chunkB;
    int f1B = min(nf, f0B + chunkB);
    int nloc = f1B - f0B;
    const float qnan = __int_as_float(0x7FC00000);
    for (int i = t; i < nloc; i += NTHR) {
        int f = f0B + i;
        int ia = faces[3 * f + 0], ib = faces[3 * f + 1], ic = faces[3 * f + 2];
        float v0[3], v1[3], v2[3];
        for (int k = 0; k < 3; ++k) {
            float cen = (k == 0) ? cx : ((k == 1) ? cy : cz);
            v0[k] = __fdiv_rn(__fsub_rn(hv[3 * ia + k], cen), sc);
            v1[k] = __fdiv_rn(__fsub_rn(hv[3 * ib + k], cen), sc);
            v2[k] = __fdiv_rn(__fsub_rn(hv[3 * ic + k], cen), sc);
        }
        float e0[3], e1[3];
        for (int k = 0; k < 3; ++k) {
            e0[k] = __fsub_rn(v1[k], v0[k]);
            e1[k] = __fsub_rn(v2[k], v0[k]);
        }
        float a = dot_rn(e0, e0);
        float b = dot_rn(e0, e1);
        float cc = dot_rn(e1, e1);
        float det = __fsub_rn(__fmul_rn(a, cc), __fmul_rn(b, b));
        // NaN-poisoned reciprocals: NaN comparisons false -> reference's forced-false
        float inv_det = (det > EPSF) ? (1.0f / det) : qnan;
        float inv_a = 1.0f / ((a > EPSF) ? a : 1.0f);
        float inv_c = 1.0f / ((cc > EPSF) ? cc : 1.0f);
        float ee2 = __fsub_rn(__fadd_rn(a, cc), __fmul_rn(2.0f, b));
        float inv_ee2 = 1.0f / ((ee2 > EPSF) ? ee2 : 1.0f);
        float det2 = __fsub_rn(__fmul_rn(e0[0], e1[1]), __fmul_rn(e1[0], e0[1]));
        float inv_det2s = (fabsf(det2) > EPSF) ? (1.0f / det2) : qnan;
        float* o = fd + (size_t)f * FS;
        o[0] = v0[0]; o[1] = v0[1]; o[2] = v0[2];
        o[3] = e0[0]; o[4] = e0[1]; o[5] = e0[2];
        o[6] = e1[0]; o[7] = e1[1]; o[8] = e1[2];
        o[9] = a; o[10] = b; o[11] = cc;
        o[12] = inv_det; o[13] = inv_a; o[14] = inv_c;
        o[15] = ee2; o[16] = inv_ee2; o[17] = inv_det2s;
        o[18] = __fsub_rn(b, a); o[19] = 0.f;
    }
    for (int i = t; i < 2048; i += NTHR) s_d2[i] = 0x7f800000u;
    if (t < 64) s_pm[t] = 0u;
    __syncthreads();   // drains vmcnt(0): fd writes visible to own block's s_loads

    // ---------- phase C: z-folded hot loop, face fields via s_load ----------
    {
        int col = cg * 64 + lane;           // gy*32+gx
        int gx = col & 31, gy = col >> 5;
        float px = __fadd_rn(-1.0f, __fmul_rn((float)gx, step));
        float py = __fadd_rn(-1.0f, __fmul_rn((float)gy, step));

        int wvu = __builtin_amdgcn_readfirstlane(wvid);

        float dmin[32];
#pragma unroll
        for (int k = 0; k < 32; ++k) dmin[k] = 3.402823466e38f;
        unsigned cmask = 0u;

        // round-robin faces across 16 waves (balanced SIMDs; min/xor commute
        // exactly so any partition is bit-exact). f is wave-uniform -> s_load.
        for (int i = wvu; i < nloc; i += 16) {
            const float* q = fd + (size_t)(f0B + i) * FS;
            float v0x = q[0], v0y = q[1], v0z = q[2];
            float e0x = q[3], e0y = q[4], e0z = q[5];
            float e1x = q[6], e1y = q[7], e1z = q[8];
            float a = q[9], b = q[10], cc = q[11];
            float inv_det = q[12], inv_a = q[13], inv_c = q[14];
            float ee2 = q[15], inv_ee2 = q[16], inv_det2s = q[17];
            float bma = q[18];

            float wx = __fsub_rn(px, v0x), wy = __fsub_rn(py, v0y);
            float ffxy = wx * wx + wy * wy;
            float de0xy = wx * e0x + wy * e0y;
            float de1xy = wx * e1x + wy * e1y;

            float u2n = __fsub_rn(__fmul_rn(wx, e1y), __fmul_rn(wy, e1x));
            float v2n = __fsub_rn(__fmul_rn(e0x, wy), __fmul_rn(e0y, wx));
            float u2 = __fmul_rn(u2n, inv_det2s);
            float v2 = __fmul_rn(v2n, inv_det2s);
            bool in2d = (u2 >= 0.0f) & (v2 >= 0.0f) & (__fadd_rn(u2, v2) <= 1.0f);
            float zint = __fadd_rn(__fadd_rn(v0z, __fmul_rn(u2, e0z)), __fmul_rn(v2, e1z));
            int c = 0;
            {
                float p;
                p = __fadd_rn(-1.0f, __fmul_rn((float)(15), step));      if (zint > p) c = 16;
                p = __fadd_rn(-1.0f, __fmul_rn((float)(c + 7), step));   if (zint > p) c += 8;
                p = __fadd_rn(-1.0f, __fmul_rn((float)(c + 3), step));   if (zint > p) c += 4;
                p = __fadd_rn(-1.0f, __fmul_rn((float)(c + 1), step));   if (zint > p) c += 2;
                p = __fadd_rn(-1.0f, __fmul_rn((float)(c), step));       if (zint > p) c += 1;
                p = __fadd_rn(-1.0f, __fmul_rn((float)(c), step));       if (zint > p) c += 1;
            }
            unsigned mask = (c == 0) ? 0u : (0xffffffffu >> (32 - c));
            cmask ^= in2d ? mask : 0u;

#pragma unroll
            for (int k = 0; k < 32; ++k) {
                const float pzk = -1.0f + (float)k * (2.0f / 31.0f);
                float wz = __fsub_rn(pzk, v0z);
                float ff = fmaf(wz, wz, ffxy);
                float de0 = fmaf(wz, e0z, de0xy);
                float de1 = fmaf(wz, e1z, de1xy);
                float u = (cc * de0 - b * de1) * inv_det;
                float v = (a * de1 - b * de0) * inv_det;
                bool inside = (u >= 0.0f) & (v >= 0.0f) & (u + v <= 1.0f);
                float plane_d2 = ff - (u * de0 + v * de1);
                float t0 = fminf(fmaxf(de0 * inv_a, 0.0f), 1.0f);
                float d2_0 = ff + t0 * (t0 * a - 2.0f * de0);
                float t1 = fminf(fmaxf(de1 * inv_c, 0.0f), 1.0f);
                float d2_1 = ff + t1 * (t1 * cc - 2.0f * de1);
                float dot2 = (de1 - de0) - bma;
                float w1sq = ff - 2.0f * de0 + a;
                float t2 = fminf(fmaxf(dot2 * inv_ee2, 0.0f), 1.0f);
                float d2_2 = w1sq + t2 * (t2 * ee2 - 2.0f * dot2);
                float ed2 = fminf(fminf(d2_0, d2_1), d2_2);
                float d2 = inside ? plane_d2 : ed2;
                dmin[k] = fminf(dmin[k], fmaxf(d2, 0.0f));
            }
        }

        // block combine (LDS), then device-scope atomics into ws buffers
#pragma unroll
        for (int k = 0; k < 32; ++k)
            atomicMin(&s_d2[k * 64 + lane], __float_as_uint(dmin[k]));
        atomicXor(&s_pm[lane], cmask);
        __syncthreads();
        for (int i = t; i < 2048; i += NTHR) {
            int k = i >> 6, ln = i & 63;
            atomicMin(&d2u[k * NCOL + cg * 64 + ln], s_d2[i]);
        }
        if (t < 64) atomicXor(&parm[cg * 64 + t], s_pm[t]);
    }

    // ---------- completion counter: last block finishes ----------
    __threadfence();
    __syncthreads();
    if (t == 0) {
        unsigned old = atomicAdd(counter, 1u);   // base 0xFFFFFFFF from memset
        s_last = (old == (unsigned)(NBLK - 2)) ? 1u : 0u;
    }
    __syncthreads();
    if (s_last == 0u) return;
    __threadfence();

    // ---------- finisher (one block): o-bbox + overlap + sample + loss ----------
    {
        float onx = INFINITY, ony = INFINITY, onz = INFINITY;
        float oxx = -INFINITY, oxy = -INFINITY, oxz = -INFINITY;
        for (int j = t; j < no; j += NTHR) {
            float x = ov[3 * j], y = ov[3 * j + 1], z = ov[3 * j + 2];
            onx = fminf(onx, x); ony = fminf(ony, y); onz = fminf(onz, z);
            oxx = fmaxf(oxx, x); oxy = fmaxf(oxy, y); oxz = fmaxf(oxz, z);
        }
        onx = wmin64(onx); ony = wmin64(ony); onz = wmin64(onz);
        oxx = wmax64(oxx); oxy = wmax64(oxy); oxz = wmax64(oxz);
        if (lane == 0) {
            s_w[wvid][0] = onx; s_w[wvid][1] = ony; s_w[wvid][2] = onz;
            s_w[wvid][3] = oxx; s_w[wvid][4] = oxy; s_w[wvid][5] = oxz;
        }
        __syncthreads();
        if (wvid == 0) {
            float a0 = (lane < 16) ? s_w[lane][0] : INFINITY;
            float a1 = (lane < 16) ? s_w[lane][1] : INFINITY;
            float a2 = (lane < 16) ? s_w[lane][2] : INFINITY;
            float a3 = (lane < 16) ? s_w[lane][3] : -INFINITY;
            float a4 = (lane < 16) ? s_w[lane][4] : -INFINITY;
            float a5 = (lane < 16) ? s_w[lane][5] : -INFINITY;
            a0 = wmin64(a0); a1 = wmin64(a1); a2 = wmin64(a2);
            a3 = wmax64(a3); a4 = wmax64(a4); a5 = wmax64(a5);
            if (lane == 0) {
                bool ovl = (s_hb[0] <= a3) && (s_hb[1] <= a4) && (s_hb[2] <= a5) &&
                           (a0 <= s_hb[3]) && (a1 <= s_hb[4]) && (a2 <= s_hb[5]);
                s_ovl = ovl ? 1.0f : 0.0f;
            }
        }
        __syncthreads();
        float acc = 0.0f;
        for (int j = t; j < no; j += NTHR) {
            float qx = __fdiv_rn(__fsub_rn(ov[3 * j + 0], cx), sc);
            float qy = __fdiv_rn(__fsub_rn(ov[3 * j + 1], cy), sc);
            float qz = __fdiv_rn(__fsub_rn(ov[3 * j + 2], cz), sc);
            float fx = __fmul_rn(__fmul_rn(__fadd_rn(qx, 1.0f), 0.5f), 31.0f);
            float fy = __fmul_rn(__fmul_rn(__fadd_rn(qy, 1.0f), 0.5f), 31.0f);
            float fz = __fmul_rn(__fmul_rn(__fadd_rn(qz, 1.0f), 0.5f), 31.0f);
            float flx = floorf(fx), fly = floorf(fy), flz = floorf(fz);
            int ix0 = (int)flx, iy0 = (int)fly, iz0 = (int)flz;
            float w1x = __fsub_rn(fx, flx), w0x = __fsub_rn(1.0f, w1x);
            float w1y = __fsub_rn(fy, fly), w0y = __fsub_rn(1.0f, w1y);
            float w1z = __fsub_rn(fz, flz), w0z = __fsub_rn(1.0f, w1z);
            for (int dz = 0; dz < 2; ++dz)
                for (int dy = 0; dy < 2; ++dy)
                    for (int dx = 0; dx < 2; ++dx) {
                        int ix = ix0 + dx, iy = iy0 + dy, iz = iz0 + dz;
                        bool valid = (ix >= 0) & (ix < GN) & (iy >= 0) & (iy < GN) &
                                     (iz >= 0) & (iz < GN);
                        if (valid) {
                            // agent-scope loads: coherent vs other XCDs' atomics
                            unsigned pmv = __hip_atomic_load(&parm[iy * GN + ix],
                                                __ATOMIC_RELAXED, __HIP_MEMORY_SCOPE_AGENT);
                            unsigned pm = pmv ^ 0xFFFFFFFFu;   // remove memset base
                            float val = 0.0f;
                            if ((pm >> iz) & 1u) {
                                unsigned du = __hip_atomic_load(&d2u[(iz * GN + iy) * GN + ix],
                                                __ATOMIC_RELAXED, __HIP_MEMORY_SCOPE_AGENT);
                                val = sqrtf(__uint_as_float(du));
                            }
                            float wgt = __fmul_rn(__fmul_rn(dx ? w1x : w0x, dy ? w1y : w0y),
                                                  dz ? w1z : w0z);
                            acc = __fadd_rn(acc, __fmul_rn(val, wgt));
                        }
                    }
        }
        acc = wsum64(acc);
        if (lane == 0) s_w[wvid][6] = acc;
        __syncthreads();
        if (wvid == 0) {
            float v = (lane < 16) ? s_w[lane][6] : 0.0f;
            v = wsum64(v);
            if (lane == 0) {
                float loss = __fmul_rn(v, v);
                out[0] = (s_ovl != 0.0f) ? loss : 0.0f;
            }
        }
    }
}

extern "C" void kernel_launch(void* const* d_in, const int* in_sizes, int n_in,
                              void* d_out, int out_size, void* d_ws, size_t ws_size,
                              hipStream_t stream) {
    const float* hv = (const float*)d_in[0];
    const float* ov = (const float*)d_in[1];
    const int* faces = (const int*)d_in[2];
    int nh = in_sizes[0] / 3;
    int no = in_sizes[1] / 3;
    int nf = in_sizes[2] / 3;

    unsigned* d2u = (unsigned*)d_ws;          // NPTS u32
    unsigned* parm = d2u + NPTS;              // NCOL u32
    unsigned* counter = parm + NCOL;          // 1 u32 (+pad)
    float* fd = (float*)(counter + 16);       // nf * FS floats

    // one node: init d2u=UINT_MAX (atomicMin top), parm=0xFFFFFFFF (XOR base,
    // removed in finisher), counter=0xFFFFFFFF (add base; 256th old == 254)
    hipMemsetAsync(d_ws, 0xFF, (size_t)(NPTS + NCOL + 16) * 4, stream);
    k_all<<<NBLK, NTHR, 0, stream>>>(hv, nh, ov, no, faces, nf,
                                     d2u, parm, counter, fd, (float*)d_out);
}